// Round 5
// baseline (322.268 us; speedup 1.0000x reference)
//
#include <hip/hip_runtime.h>

#define CRF_B 1024
#define CRF_T 512
#define CRF_K 64
#define CRF_START 62
#define CRF_STOP 63

typedef float vf16 __attribute__((ext_vector_type(16)));

__device__ __forceinline__ float bcastf(float v, int lane) {
  return __int_as_float(__builtin_amdgcn_readlane(__float_as_int(v), lane));
}

__device__ __forceinline__ float wave_sum64(float v) {
#pragma unroll
  for (int off = 32; off > 0; off >>= 1) v += __shfl_xor(v, off, 64);
  return v;
}

// One block per batch: wave0 = forward recurrence (exp domain), wave1 =
// gold-path score (fully parallel). out += (fwd - gold)/B.
//
// R4 post-mortem: readlane-based broadcast (63x f32 or 32x f16 dot2) pins the
// step at ~700cyc regardless of MAC count -> broadcast mechanism is the
// bottleneck, not issue. This round: P broadcast via LDS wave-uniform reads
// (1 ds_write_b32 + 16 ds_read_b128; same-address reads are HW broadcast,
// conflict-free, DS pipe overlaps the VALU fma stream).
__global__ __launch_bounds__(128, 1) void crf_kernel(
    const float* __restrict__ feats, const int* __restrict__ lengths,
    const int* __restrict__ tags, const float* __restrict__ trans,
    float* __restrict__ out) {
  __shared__ float sT[CRF_K * 65];  // stride 65: conflict-free + gold reads
  __shared__ float sP[CRF_K];       // wave0's P broadcast buffer

  const int b = blockIdx.x;
  const int tid = threadIdx.x;
  const int lane = tid & 63;

  for (int idx = tid; idx < CRF_K * CRF_K; idx += 128)
    sT[(idx >> 6) * 65 + (idx & 63)] = trans[idx];
  __syncthreads();

  const int L = lengths[b];

  if (tid < 64) {
    // ---------------- forward wave (exp domain) ----------------
    // lane i holds E row i = exp(trans[i][0..63]) (exp(-10000)=0 exactly:
    // column STOP and row START are exact zeros).
    vf16 E0, E1, E2, E3;
    {
      const float* trow = &sT[lane * 65];
#pragma unroll
      for (int j = 0; j < 16; ++j) E0[j] = __expf(trow[j]);
#pragma unroll
      for (int j = 0; j < 16; ++j) E1[j] = __expf(trow[16 + j]);
#pragma unroll
      for (int j = 0; j < 16; ++j) E2[j] = __expf(trow[32 + j]);
#pragma unroll
      for (int j = 0; j < 16; ++j) E3[j] = __expf(trow[48 + j]);
    }

    const float* bfeats = feats + (size_t)b * CRF_T * CRF_K + lane;

    float P = (lane == CRF_START) ? 1.0f : 0.0f;  // P[i] = exp(alpha[i]-offset)
    float offset = 0.0f;

    float e[8], f[8];
#pragma unroll
    for (int r = 0; r < 8; ++r) e[r] = bfeats[r * CRF_K];

    // one step: P' = (E . P) * exp(emit), P broadcast through LDS.
    // Column STOP of E is exactly 0 -> skip j=63.
    auto do_step = [&](float ee) {
      sP[lane] = P;  // ds_write_b32; DS pipe is in-order per wave
      const float4* sp4 = (const float4*)sP;
      float a0 = 0.f, a1 = 0.f, a2 = 0.f, a3 = 0.f;
#pragma unroll
      for (int jp = 0; jp < 16; ++jp) {
        float4 q = sp4[jp];  // lane-invariant addr -> HW broadcast, 0 conflicts
        float e0, e1, e2, e3;
        if (jp < 4) {
          e0 = E0[4 * jp]; e1 = E0[4 * jp + 1]; e2 = E0[4 * jp + 2]; e3 = E0[4 * jp + 3];
        } else if (jp < 8) {
          e0 = E1[4 * jp - 16]; e1 = E1[4 * jp - 15]; e2 = E1[4 * jp - 14]; e3 = E1[4 * jp - 13];
        } else if (jp < 12) {
          e0 = E2[4 * jp - 32]; e1 = E2[4 * jp - 31]; e2 = E2[4 * jp - 30]; e3 = E2[4 * jp - 29];
        } else {
          e0 = E3[4 * jp - 48]; e1 = E3[4 * jp - 47]; e2 = E3[4 * jp - 46]; e3 = E3[4 * jp - 45];
        }
        a0 = __builtin_fmaf(e0, q.x, a0);
        a1 = __builtin_fmaf(e1, q.y, a1);
        a2 = __builtin_fmaf(e2, q.z, a2);
        if (jp < 15) a3 = __builtin_fmaf(e3, q.w, a3);  // skip j=63 (STOP col)
      }
      P = ((a0 + a1) + (a2 + a3)) * ee;
    };

    // rescale by lane 0's P (LSE identity holds for ANY finite wave-uniform
    // normalizer; P[0] > 0 after step 1 since only row START of E is all-zero)
    auto rescale = [&](int first) {
      float M = first ? 1.0f : bcastf(P, 0);
      offset += __logf(M);
      P *= __builtin_amdgcn_rcpf(M);
    };

    const int Lb = L & ~7;
    for (int t0 = 0; t0 < Lb; t0 += 8) {
      const int tn = t0 + 8;
      if (tn < CRF_T) {  // prefetch next 8 emits (wave-uniform branch)
#pragma unroll
        for (int r = 0; r < 8; ++r) f[r] = bfeats[(tn + r) * CRF_K];
      } else {
#pragma unroll
        for (int r = 0; r < 8; ++r) f[r] = 0.0f;
      }
      float ee[8];
#pragma unroll
      for (int r = 0; r < 8; ++r) ee[r] = __expf(e[r]);  // off-chain

      rescale(t0 == 0);  // growth over 8 steps ~e^64 < f32 max (R2/R3 verified)

#pragma unroll
      for (int r = 0; r < 8; ++r) do_step(ee[r]);
#pragma unroll
      for (int r = 0; r < 8; ++r) e[r] = f[r];
    }
    if (Lb < L) {  // tail (<= 7 steps)
      rescale(Lb == 0);
#pragma unroll
      for (int r = 0; r < 8; ++r)
        if (Lb + r < L) do_step(__expf(e[r]));
    }

    // terminal: fwd = offset + log( sum_i P[i] * exp(trans[STOP][i]) )
    float eST = __expf(sT[CRF_STOP * 65 + lane]);  // exp(-10000)=0 kills i=STOP
    float s2 = wave_sum64(P * eST);
    float fwd = offset + __logf(s2);
    if (lane == 0) atomicAdd(out, fwd * (1.0f / CRF_B));
  } else {
    // ---------------- gold wave (fully parallel) ----------------
    const int* btags = tags + b * CRF_T;
    const float* bf = feats + (size_t)b * CRF_T * CRF_K;
    float gold = 0.0f;
#pragma unroll
    for (int base = 0; base < CRF_T; base += 64) {
      int t = base + lane;
      if (t < L) {
        int tg = btags[t];
        int tp = (t == 0) ? CRF_START : btags[t - 1];
        gold += bf[(size_t)t * CRF_K + tg];  // emit
        gold += sT[tg * 65 + tp];            // transition
      }
    }
    gold = wave_sum64(gold);
    if (lane == 0) {
      gold += sT[CRF_STOP * 65 + btags[L - 1]];  // terminal transition
      atomicAdd(out, -gold * (1.0f / CRF_B));
    }
  }
}

extern "C" void kernel_launch(void* const* d_in, const int* in_sizes, int n_in,
                              void* d_out, int out_size, void* d_ws, size_t ws_size,
                              hipStream_t stream) {
  const float* feats = (const float*)d_in[0];
  const int* lengths = (const int*)d_in[1];
  const int* tags = (const int*)d_in[2];
  const float* trans = (const float*)d_in[3];
  float* out = (float*)d_out;
  hipMemsetAsync(out, 0, sizeof(float), stream);
  crf_kernel<<<CRF_B, 128, 0, stream>>>(feats, lengths, tags, trans, out);
}

// Round 6
// 314.418 us; speedup vs baseline: 1.0250x; 1.0250x over previous
//
#include <hip/hip_runtime.h>

#define CRF_B 1024
#define CRF_T 512
#define CRF_K 64
#define CRF_START 62
#define CRF_STOP 63

typedef float vf16 __attribute__((ext_vector_type(16)));

__device__ __forceinline__ float bcastf(float v, int lane) {
  return __int_as_float(__builtin_amdgcn_readlane(__float_as_int(v), lane));
}

__device__ __forceinline__ float wave_sum64(float v) {
#pragma unroll
  for (int off = 32; off > 0; off >>= 1) v += __shfl_xor(v, off, 64);
  return v;
}

// One 64-thread block per sequence. Gold path in the prologue (lane-per-t,
// global gathers), then the exp-domain forward recurrence.
//
// R5 post-mortem: per-step cost ~1000cyc with DS-stall arithmetic matching
// ~50cyc exposed latency per ds_read (compiler interleaved read/wait/fma).
// R6: (1) ALL 16 broadcast reads batched into q[16] before any fma ->
// single exposed latency + fine-grained lgkmcnt; (2) 64-thread blocks with
// __launch_bounds__(64,1) -> 256 arch-VGPR budget so E stays out of AGPRs
// (R3/R5 showed VGPR_Count 48/80 -> E demoted).
__global__ __launch_bounds__(64, 1) void crf_kernel(
    const float* __restrict__ feats, const int* __restrict__ lengths,
    const int* __restrict__ tags, const float* __restrict__ trans,
    float* __restrict__ out) {
  __shared__ float sP[CRF_K];  // P broadcast buffer (single wave, in-order DS)

  const int b = blockIdx.x;
  const int lane = threadIdx.x;
  const int L = lengths[b];

  // ---- E rows from global (L2-resident after first blocks) ----
  const float* trow = trans + lane * CRF_K;
  vf16 E0, E1, E2, E3;
#pragma unroll
  for (int j = 0; j < 16; ++j) E0[j] = __expf(trow[j]);
#pragma unroll
  for (int j = 0; j < 16; ++j) E1[j] = __expf(trow[16 + j]);
#pragma unroll
  for (int j = 0; j < 16; ++j) E2[j] = __expf(trow[32 + j]);
#pragma unroll
  for (int j = 0; j < 16; ++j) E3[j] = __expf(trow[48 + j]);

  // ---- gold-path score (fully parallel prologue, no LDS) ----
  const int* btags = tags + b * CRF_T;
  const float* bf = feats + (size_t)b * CRF_T * CRF_K;
  float gold = 0.0f;
#pragma unroll
  for (int base = 0; base < CRF_T; base += 64) {
    int t = base + lane;
    if (t < L) {
      int tg = btags[t];
      int tp = (t == 0) ? CRF_START : btags[t - 1];
      gold += bf[(size_t)t * CRF_K + tg];  // emit
      gold += trans[tg * CRF_K + tp];      // transition (L2)
    }
  }
  gold = wave_sum64(gold);

  // ---- forward recurrence (exp domain) ----
  const float* bfeats = bf + lane;
  float P = (lane == CRF_START) ? 1.0f : 0.0f;  // P[i] = exp(alpha[i]-offset)
  float offset = 0.0f;

  float e[8], f[8];
#pragma unroll
  for (int r = 0; r < 8; ++r) e[r] = bfeats[r * CRF_K];

  // one step: P' = (E . P) * exp(emit). Column STOP of E is exactly 0 -> skip
  // j=63. All 16 broadcast reads issued BEFORE any fma (the round's theory).
  auto do_step = [&](float ee) {
    sP[lane] = P;  // ds_write_b32; same-wave DS ordering makes reads safe
    const float4* sp4 = (const float4*)sP;
    float4 q[16];
#pragma unroll
    for (int jp = 0; jp < 16; ++jp) q[jp] = sp4[jp];  // 16x ds_read_b128, batched
    float a0 = 0.f, a1 = 0.f, a2 = 0.f, a3 = 0.f;
#pragma unroll
    for (int jp = 0; jp < 16; ++jp) {
      float e0, e1, e2, e3;
      if (jp < 4) {
        e0 = E0[4 * jp]; e1 = E0[4 * jp + 1]; e2 = E0[4 * jp + 2]; e3 = E0[4 * jp + 3];
      } else if (jp < 8) {
        e0 = E1[4 * jp - 16]; e1 = E1[4 * jp - 15]; e2 = E1[4 * jp - 14]; e3 = E1[4 * jp - 13];
      } else if (jp < 12) {
        e0 = E2[4 * jp - 32]; e1 = E2[4 * jp - 31]; e2 = E2[4 * jp - 30]; e3 = E2[4 * jp - 29];
      } else {
        e0 = E3[4 * jp - 48]; e1 = E3[4 * jp - 47]; e2 = E3[4 * jp - 46]; e3 = E3[4 * jp - 45];
      }
      a0 = __builtin_fmaf(e0, q[jp].x, a0);
      a1 = __builtin_fmaf(e1, q[jp].y, a1);
      a2 = __builtin_fmaf(e2, q[jp].z, a2);
      if (jp < 15) a3 = __builtin_fmaf(e3, q[jp].w, a3);  // skip j=63 (STOP col)
    }
    P = ((a0 + a1) + (a2 + a3)) * ee;
  };

  // rescale by lane 0's P (LSE identity holds for ANY finite wave-uniform
  // normalizer; P[0] > 0 after step 1 since only row START of E is all-zero)
  auto rescale = [&](int first) {
    float M = first ? 1.0f : bcastf(P, 0);
    offset += __logf(M);
    P *= __builtin_amdgcn_rcpf(M);
  };

  const int Lb = L & ~7;
  for (int t0 = 0; t0 < Lb; t0 += 8) {
    const int tn = t0 + 8;
    if (tn < CRF_T) {  // prefetch next 8 emits (wave-uniform branch)
#pragma unroll
      for (int r = 0; r < 8; ++r) f[r] = bfeats[(tn + r) * CRF_K];
    } else {
#pragma unroll
      for (int r = 0; r < 8; ++r) f[r] = 0.0f;
    }
    float ee[8];
#pragma unroll
    for (int r = 0; r < 8; ++r) ee[r] = __expf(e[r]);  // off-chain

    rescale(t0 == 0);  // growth over 8 steps stays in f32 range (R2-R5 verified)

#pragma unroll
    for (int r = 0; r < 8; ++r) do_step(ee[r]);
#pragma unroll
    for (int r = 0; r < 8; ++r) e[r] = f[r];
  }
  if (Lb < L) {  // tail (<= 7 steps)
    rescale(Lb == 0);
#pragma unroll
    for (int r = 0; r < 8; ++r)
      if (Lb + r < L) do_step(__expf(e[r]));
  }

  // terminal: fwd = offset + log( sum_i P[i] * exp(trans[STOP][i]) )
  float eST = __expf(trans[CRF_STOP * CRF_K + lane]);  // exp(-10000)=0 kills i=STOP
  float s2 = wave_sum64(P * eST);
  float fwd = offset + __logf(s2);

  if (lane == 0) {
    gold += trans[CRF_STOP * CRF_K + btags[L - 1]];  // terminal transition
    atomicAdd(out, (fwd - gold) * (1.0f / CRF_B));
  }
}

extern "C" void kernel_launch(void* const* d_in, const int* in_sizes, int n_in,
                              void* d_out, int out_size, void* d_ws, size_t ws_size,
                              hipStream_t stream) {
  const float* feats = (const float*)d_in[0];
  const int* lengths = (const int*)d_in[1];
  const int* tags = (const int*)d_in[2];
  const float* trans = (const float*)d_in[3];
  float* out = (float*)d_out;
  hipMemsetAsync(out, 0, sizeof(float), stream);
  crf_kernel<<<CRF_B, 64, 0, stream>>>(feats, lengths, tags, trans, out);
}